// Round 6
// baseline (876.971 us; speedup 1.0000x reference)
//
#include <hip/hip_runtime.h>
#include <hip/hip_bf16.h>

typedef __hip_bfloat16 bf16;
typedef __attribute__((ext_vector_type(8))) short bf16x8;   // 8 bf16 = 4 VGPR (MFMA A/B frag)
typedef __attribute__((ext_vector_type(4))) float f32x4;    // MFMA C/D frag
typedef __attribute__((ext_vector_type(8))) unsigned short us8;

#define NB 4
#define NS 2048
#define ND 1024
#define NH 16
#define NDK 64
#define NM (NB * NS)   // 8192

// async global->LDS, 16B per lane; LDS dest is wave-uniform base + lane*16
__device__ __forceinline__ void async16(const bf16* g, bf16* l) {
  __builtin_amdgcn_global_load_lds(
      (const __attribute__((address_space(1))) void*)g,
      (__attribute__((address_space(3))) void*)l, 16, 0, 0);
}

// ---------------------------------------------------------------------------
// Kernel 0: f32 -> bf16 conversion of x and the 4 weight matrices.
// ---------------------------------------------------------------------------
__global__ __launch_bounds__(256) void conv_kernel(
    const float* __restrict__ x, const float* __restrict__ wq,
    const float* __restrict__ wk, const float* __restrict__ wv,
    const float* __restrict__ wo, bf16* __restrict__ xb,
    bf16* __restrict__ qb, bf16* __restrict__ kb, bf16* __restrict__ vb,
    bf16* __restrict__ ob) {
  const int bid = blockIdx.x;
  const float* src;
  bf16* dst;
  int base;
  if (bid < 4096) {
    src = x; dst = xb; base = bid;
  } else {
    const int t = bid - 4096;
    const int w = t >> 9;
    base = t & 511;
    src = (w == 0) ? wq : (w == 1) ? wk : (w == 2) ? wv : wo;
    dst = (w == 0) ? qb : (w == 1) ? kb : (w == 2) ? vb : ob;
  }
  const size_t off = (size_t)base * 2048 + (size_t)threadIdx.x * 8;
  const float4 a = *(const float4*)(src + off);
  const float4 b = *(const float4*)(src + off + 4);
  us8 pk;
  float va[8] = {a.x, a.y, a.z, a.w, b.x, b.y, b.z, b.w};
#pragma unroll
  for (int i = 0; i < 8; ++i) {
    bf16 h = __float2bfloat16(va[i]);
    pk[i] = *(unsigned short*)&h;
  }
  *(us8*)(dst + off) = pk;
}

// ---------------------------------------------------------------------------
// Kernel 1: fused QKV projection + RoPE.  Y = x @ W^T.
// grid (24, 64): x = which*8 + ntile, y = mtile.  128x128 tile, BK=64, 4 waves.
// Q is additionally scaled by 1/sqrt(DK) (folded from attention).
// Epilogue stages the tile in LDS and writes coalesced 16B stores.
// ---------------------------------------------------------------------------
__global__ __launch_bounds__(256, 2) void qkv_kernel(
    const bf16* __restrict__ x, const bf16* __restrict__ Wq,
    const bf16* __restrict__ Wk, const bf16* __restrict__ Wv,
    const int* __restrict__ pos, bf16* __restrict__ Qo, bf16* __restrict__ Ko,
    bf16* __restrict__ Vo) {
  const int tid = threadIdx.x;
  const int wid = tid >> 6, lane = tid & 63;
  const int lr = lane & 15;              // frag row/col
  const int lk = (lane >> 4) << 3;       // frag k offset
  const int wm = wid >> 1, wn = wid & 1; // 2x2 wave grid
  const int m0 = blockIdx.y << 7;
  const int which = blockIdx.x >> 3;     // 0=Q 1=K 2=V
  const int n0 = (blockIdx.x & 7) << 7;  // feature tile within the 1024
  const bf16* W = (which == 0) ? Wq : (which == 1) ? Wk : Wv;

  __shared__ __align__(16) unsigned char smem_raw[128 * 136 * 2];  // 34816 B
  bf16* sA = (bf16*)smem_raw;              // [128][64] main-loop A
  bf16* sB = (bf16*)(smem_raw + 16384);    // [128][64] main-loop B

  f32x4 acc[4][4];
#pragma unroll
  for (int i = 0; i < 4; ++i)
#pragma unroll
    for (int j = 0; j < 4; ++j) acc[i][j] = (f32x4){0.f, 0.f, 0.f, 0.f};

  const int srow = lane >> 3;        // 0..7
  const int scol = (lane & 7) << 3;  // 0..56

  for (int k0 = 0; k0 < ND; k0 += 64) {
    __syncthreads();
#pragma unroll
    for (int c = 0; c < 4; ++c) {
      const int chunk = (wid << 2) + c;      // 0..15
      const int row = (chunk << 3) + srow;   // 0..127
      async16(x + (size_t)(m0 + row) * ND + k0 + scol, &sA[chunk << 9]);
      async16(W + (size_t)(n0 + row) * ND + k0 + scol, &sB[chunk << 9]);
    }
    __syncthreads();
#pragma unroll
    for (int ks = 0; ks < 2; ++ks) {
      bf16x8 af[4], bfr[4];
#pragma unroll
      for (int mi = 0; mi < 4; ++mi)
        af[mi] = *(const bf16x8*)&sA[((wm << 6) + (mi << 4) + lr) * 64 + (ks << 5) + lk];
#pragma unroll
      for (int ni = 0; ni < 4; ++ni)
        bfr[ni] = *(const bf16x8*)&sB[((wn << 6) + (ni << 4) + lr) * 64 + (ks << 5) + lk];
#pragma unroll
      for (int mi = 0; mi < 4; ++mi)
#pragma unroll
        for (int ni = 0; ni < 4; ++ni)
          acc[mi][ni] = __builtin_amdgcn_mfma_f32_16x16x32_bf16(af[mi], bfr[ni], acc[mi][ni], 0, 0, 0);
    }
  }

  // ---- epilogue: RoPE in-register -> LDS stage -> coalesced 16B stores ----
  const int rbase = (lane >> 4) << 2;  // C/D: row=(lane>>4)*4+r, col=lane&15
  const int b = m0 >> 11;              // single batch per block (128 | 2048)
  const int s0g = m0 & (NS - 1);
  const int h0 = n0 >> 6;              // two heads per 128-col tile
  const float oscale = (which == 0) ? 0.125f : 1.0f;  // 1/sqrt(64) into Q

  __syncthreads();                     // all sA/sB reads done before overwrite
  bf16* st = (bf16*)smem_raw;          // [128][136] stage

  if (which == 2) {
    // V: stage TRANSPOSED [dkfull 0..127][srow 0..127]
#pragma unroll
    for (int mi = 0; mi < 4; ++mi) {
      const int sr = (wm << 6) + (mi << 4) + rbase;
#pragma unroll
      for (int ni = 0; ni < 4; ++ni) {
        const int dkfull = (wn << 6) + (ni << 4) + lr;
#pragma unroll
        for (int r = 0; r < 4; ++r)
          st[dkfull * 136 + sr + r] = __float2bfloat16(acc[mi][ni][r]);
      }
    }
  } else {
#pragma unroll
    for (int mi = 0; mi < 4; ++mi) {
      const int sr = (wm << 6) + (mi << 4) + rbase;
#pragma unroll
      for (int ni = 0; ni < 4; ++ni) {
        const int col = (wn << 6) + (ni << 4) + lr;  // 0..127
        const int dk = col & 63;
        // inv_freq = 10000^(-(dk/2)/32) = 2^(-(dk/2)*log2(1e4)/32)
        const float invf = exp2f(-(float)(dk >> 1) * 0.4152410118609203f);
#pragma unroll
        for (int r = 0; r < 4; ++r) {
          float v = acc[mi][ni][r];
          float other = __shfl_xor(v, 1);  // partner column (dk^1)
          const int s = s0g + sr + r;
          float ang = (float)pos[s] * invf;
          float sn, cn;
          sincosf(ang, &sn, &cn);
          float res = (dk & 1) ? fmaf(other, sn, v * cn) : fmaf(v, cn, -(other * sn));
          st[(sr + r) * 136 + col] = __float2bfloat16(res * oscale);
        }
      }
    }
  }
  __syncthreads();

  if (which == 2) {
    // write V^T (bh, dk, s): 2 planes x 64 dk-rows x 256B contiguous
#pragma unroll
    for (int i = 0; i < 8; ++i) {
      const int g = (i << 8) + tid;
      const int plane = g >> 10, dkr = (g >> 4) & 63, seg = g & 15;
      us8 v = *(const us8*)&st[(plane * 64 + dkr) * 136 + (seg << 3)];
      *(us8*)&Vo[((size_t)(b * NH + h0 + plane) * NDK + dkr) * NS + s0g + (seg << 3)] = v;
    }
  } else {
    bf16* dst = (which == 0) ? Qo : Ko;
    // write (bh, s, dk): 2 planes x 128 s-rows x 128B contiguous
#pragma unroll
    for (int i = 0; i < 8; ++i) {
      const int g = (i << 8) + tid;
      const int plane = g >> 10, row = (g >> 3) & 127, seg = g & 7;
      us8 v = *(const us8*)&st[row * 136 + (plane << 6) + (seg << 3)];
      *(us8*)&dst[((size_t)(b * NH + h0 + plane) * NS + s0g + row) * NDK + (seg << 3)] = v;
    }
  }
}

// ---------------------------------------------------------------------------
// Kernel 2: causal flash attention.
// grid (8, 64), 512 threads (8 waves). Waves 0-3 own q-tile x, waves 4-7 own
// q-tile 15-x  => per-block work is CONSTANT (causal pairing), 2 blocks/CU,
// all blocks resident, no barriers (per-wave P buffers).
// Per wave: 32 q-rows; KV tiles of 64; in-place register prefetch of K/V
// frags for tile t+1 issued right after their last use in tile t.
// Row-sum via MFMA with a ones-fragment (C-layout rows align with lrun).
// Scale 1/sqrt(dk) is pre-folded into Q by qkv_kernel.
// ---------------------------------------------------------------------------
__global__ __launch_bounds__(512, 4) void attn_kernel(
    const bf16* __restrict__ Q, const bf16* __restrict__ K,
    const bf16* __restrict__ V, bf16* __restrict__ O) {
  const int tid = threadIdx.x;
  const int wid = tid >> 6, lane = tid & 63;
  const int lr = lane & 15, lk = (lane >> 4) << 3;
  const int rbase = (lane >> 4) << 2;
  const int bh = blockIdx.y;
  const int qt = (wid < 4) ? blockIdx.x : (15 - blockIdx.x);
  const int qw = (qt << 7) + ((wid & 3) << 5);  // wave's q base (32 rows)

  const bf16* Qb = Q + (size_t)bh * NS * NDK;
  const bf16* Kb = K + (size_t)bh * NS * NDK;
  const bf16* Vb = V + (size_t)bh * NS * NDK;  // [64][2048]
  bf16* Ob = O + (size_t)bh * NS * NDK;

  __shared__ bf16 sP[8][32 * 72];  // per-wave P buffer, stride 72 (16B mult)
  bf16* Pw = &sP[wid][0];

  bf16x8 qf[2][2];
#pragma unroll
  for (int mi = 0; mi < 2; ++mi)
#pragma unroll
    for (int ks = 0; ks < 2; ++ks)
      qf[mi][ks] = *(const bf16x8*)&Qb[(size_t)(qw + (mi << 4) + lr) * NDK + (ks << 5) + lk];

  bf16x8 ones;
#pragma unroll
  for (int i = 0; i < 8; ++i) ones[i] = (short)0x3F80;  // bf16 1.0

  f32x4 o[2][4];
  float mrun[2][4], lrun[2][4];
#pragma unroll
  for (int mi = 0; mi < 2; ++mi)
#pragma unroll
    for (int j = 0; j < 4; ++j) {
      o[mi][j] = (f32x4){0.f, 0.f, 0.f, 0.f};
      mrun[mi][j] = -1e30f;
      lrun[mi][j] = 0.f;
    }

  const float L2E = 1.44269504f;
  const int ntiles = ((qw + 31) >> 6) + 1;

  // prologue: K/V frags for tile 0
  bf16x8 kf[4][2], vf[4][2];
#pragma unroll
  for (int nj = 0; nj < 4; ++nj)
#pragma unroll
    for (int ks = 0; ks < 2; ++ks) {
      kf[nj][ks] = *(const bf16x8*)&Kb[(size_t)((nj << 4) + lr) * NDK + (ks << 5) + lk];
      vf[nj][ks] = *(const bf16x8*)&Vb[(size_t)((nj << 4) + lr) * NS + (ks << 5) + lk];
    }

  for (int t = 0; t < ntiles; ++t) {
    const int kv0 = t << 6;
    // ---- QK^T ----
    f32x4 sc[2][4];
#pragma unroll
    for (int mi = 0; mi < 2; ++mi)
#pragma unroll
      for (int nj = 0; nj < 4; ++nj) sc[mi][nj] = (f32x4){0.f, 0.f, 0.f, 0.f};
#pragma unroll
    for (int ks = 0; ks < 2; ++ks)
#pragma unroll
      for (int nj = 0; nj < 4; ++nj)
#pragma unroll
        for (int mi = 0; mi < 2; ++mi)
          sc[mi][nj] = __builtin_amdgcn_mfma_f32_16x16x32_bf16(qf[mi][ks], kf[nj][ks], sc[mi][nj], 0, 0, 0);

    // ---- prefetch next K frags (in place; WAR keeps order) ----
    if (t + 1 < ntiles) {
      const int nk = (t + 1) << 6;
#pragma unroll
      for (int nj = 0; nj < 4; ++nj)
#pragma unroll
        for (int ks = 0; ks < 2; ++ks)
          kf[nj][ks] = *(const bf16x8*)&Kb[(size_t)(nk + (nj << 4) + lr) * NDK + (ks << 5) + lk];
    }

    // ---- mask (last tile only) + row max ----
    float mnew[2][4];
#pragma unroll
    for (int mi = 0; mi < 2; ++mi)
#pragma unroll
      for (int r = 0; r < 4; ++r) mnew[mi][r] = mrun[mi][r];
    if (t == ntiles - 1) {
#pragma unroll
      for (int mi = 0; mi < 2; ++mi)
#pragma unroll
        for (int nj = 0; nj < 4; ++nj) {
          const int col = kv0 + (nj << 4) + lr;
#pragma unroll
          for (int r = 0; r < 4; ++r) {
            const int row = qw + (mi << 4) + rbase + r;
            float s = sc[mi][nj][r];
            if (col > row) s = -1e30f;
            sc[mi][nj][r] = s;
            mnew[mi][r] = fmaxf(mnew[mi][r], s);
          }
        }
    } else {
#pragma unroll
      for (int mi = 0; mi < 2; ++mi)
#pragma unroll
        for (int nj = 0; nj < 4; ++nj)
#pragma unroll
          for (int r = 0; r < 4; ++r)
            mnew[mi][r] = fmaxf(mnew[mi][r], sc[mi][nj][r]);
    }
    float alf[2][4];
#pragma unroll
    for (int mi = 0; mi < 2; ++mi)
#pragma unroll
      for (int r = 0; r < 4; ++r) {
        float v = mnew[mi][r];
        v = fmaxf(v, __shfl_xor(v, 1));
        v = fmaxf(v, __shfl_xor(v, 2));
        v = fmaxf(v, __shfl_xor(v, 4));
        v = fmaxf(v, __shfl_xor(v, 8));
        alf[mi][r] = exp2f((mrun[mi][r] - v) * L2E);
        mrun[mi][r] = v;
#pragma unroll
        for (int dj = 0; dj < 4; ++dj) o[mi][dj][r] *= alf[mi][r];
      }

    // ---- exp + P -> LDS (bf16, C-layout scatter) ----
#pragma unroll
    for (int mi = 0; mi < 2; ++mi)
#pragma unroll
      for (int nj = 0; nj < 4; ++nj)
#pragma unroll
        for (int r = 0; r < 4; ++r) {
          float e = exp2f((sc[mi][nj][r] - mrun[mi][r]) * L2E);
          Pw[((mi << 4) + rbase + r) * 72 + (nj << 4) + lr] = __float2bfloat16(e);
        }

    // ---- P read (A-frag) + row-sum via ones-MFMA + PV ----
    bf16x8 pa[2][2];
#pragma unroll
    for (int mi = 0; mi < 2; ++mi)
#pragma unroll
      for (int ks = 0; ks < 2; ++ks)
        pa[mi][ks] = *(const bf16x8*)&Pw[((mi << 4) + lr) * 72 + (ks << 5) + lk];

#pragma unroll
    for (int mi = 0; mi < 2; ++mi) {
      f32x4 ls = (f32x4){0.f, 0.f, 0.f, 0.f};
      ls = __builtin_amdgcn_mfma_f32_16x16x32_bf16(pa[mi][0], ones, ls, 0, 0, 0);
      ls = __builtin_amdgcn_mfma_f32_16x16x32_bf16(pa[mi][1], ones, ls, 0, 0, 0);
#pragma unroll
      for (int r = 0; r < 4; ++r)
        lrun[mi][r] = fmaf(lrun[mi][r], alf[mi][r], ls[r]);
    }

#pragma unroll
    for (int ks = 0; ks < 2; ++ks)
#pragma unroll
      for (int dj = 0; dj < 4; ++dj)
#pragma unroll
        for (int mi = 0; mi < 2; ++mi)
          o[mi][dj] = __builtin_amdgcn_mfma_f32_16x16x32_bf16(pa[mi][ks], vf[dj][ks], o[mi][dj], 0, 0, 0);

    // ---- prefetch next V frags ----
    if (t + 1 < ntiles) {
      const int nk = (t + 1) << 6;
#pragma unroll
      for (int dj = 0; dj < 4; ++dj)
#pragma unroll
        for (int ks = 0; ks < 2; ++ks)
          vf[dj][ks] = *(const bf16x8*)&Vb[(size_t)((dj << 4) + lr) * NS + nk + (ks << 5) + lk];
    }
  }

  // ---- epilogue: normalize into Pw (per-wave), coalesced 16B stores ----
#pragma unroll
  for (int mi = 0; mi < 2; ++mi)
#pragma unroll
    for (int r = 0; r < 4; ++r) {
      const float inv = 1.f / lrun[mi][r];
      const int row = (mi << 4) + rbase + r;
#pragma unroll
      for (int dj = 0; dj < 4; ++dj)
        Pw[row * 72 + (dj << 4) + lr] = __float2bfloat16(o[mi][dj][r] * inv);
    }
#pragma unroll
  for (int i = 0; i < 4; ++i) {
    const int g = (i << 6) + lane;          // 256 granules: 32 rows x 8 segs
    const int row = g >> 3, seg = g & 7;
    us8 v = *(const us8*)&Pw[row * 72 + (seg << 3)];
    *(us8*)&Ob[(size_t)(qw + row) * NDK + (seg << 3)] = v;
  }
}

// ---------------------------------------------------------------------------
// Kernel 3: output projection.  out = attnO @ Wo^T (f32 out).  grid (8, 64).
// Epilogue: two-pass LDS staging, float4 coalesced stores.
// ---------------------------------------------------------------------------
__global__ __launch_bounds__(256, 2) void oproj_kernel(
    const bf16* __restrict__ AO, const bf16* __restrict__ Wo,
    float* __restrict__ out) {
  const int tid = threadIdx.x;
  const int wid = tid >> 6, lane = tid & 63;
  const int lr = lane & 15, lk = (lane >> 4) << 3;
  const int wm = wid >> 1, wn = wid & 1;
  const int m0 = blockIdx.y << 7;
  const int n0 = blockIdx.x << 7;

  __shared__ __align__(16) unsigned char smem_raw[64 * 132 * 4];  // 33792 B
  bf16* sA = (bf16*)smem_raw;
  bf16* sB = (bf16*)(smem_raw + 16384);

  f32x4 acc[4][4];
#pragma unroll
  for (int i = 0; i < 4; ++i)
#pragma unroll
    for (int j = 0; j < 4; ++j) acc[i][j] = (f32x4){0.f, 0.f, 0.f, 0.f};

  const int srow = lane >> 3;
  const int scol = (lane & 7) << 3;

  for (int k0 = 0; k0 < ND; k0 += 64) {
    __syncthreads();
    const int h = k0 >> 6;
#pragma unroll
    for (int c = 0; c < 4; ++c) {
      const int chunk = (wid << 2) + c;
      const int row = (chunk << 3) + srow;
      const int m = m0 + row;
      async16(AO + ((size_t)((m >> 11) * NH + h) * NS + (m & (NS - 1))) * NDK + scol,
              &sA[chunk << 9]);
      async16(Wo + (size_t)(n0 + row) * ND + k0 + scol, &sB[chunk << 9]);
    }
    __syncthreads();
#pragma unroll
    for (int ks = 0; ks < 2; ++ks) {
      bf16x8 af[4], bfr[4];
#pragma unroll
      for (int mi = 0; mi < 4; ++mi)
        af[mi] = *(const bf16x8*)&sA[((wm << 6) + (mi << 4) + lr) * 64 + (ks << 5) + lk];
#pragma unroll
      for (int ni = 0; ni < 4; ++ni)
        bfr[ni] = *(const bf16x8*)&sB[((wn << 6) + (ni << 4) + lr) * 64 + (ks << 5) + lk];
#pragma unroll
      for (int mi = 0; mi < 4; ++mi)
#pragma unroll
        for (int ni = 0; ni < 4; ++ni)
          acc[mi][ni] = __builtin_amdgcn_mfma_f32_16x16x32_bf16(af[mi], bfr[ni], acc[mi][ni], 0, 0, 0);
    }
  }

  // ---- epilogue: two-pass f32 LDS stage + float4 stores ----
  const int rbase = (lane >> 4) << 2;
  float* stf = (float*)smem_raw;  // [64][132]
#pragma unroll
  for (int pass = 0; pass < 2; ++pass) {
    __syncthreads();
    if (wm == pass) {
#pragma unroll
      for (int mi = 0; mi < 4; ++mi) {
        const int rloc = (mi << 4) + rbase;  // 0..63 within half-tile
#pragma unroll
        for (int ni = 0; ni < 4; ++ni) {
          const int col = (wn << 6) + (ni << 4) + lr;
#pragma unroll
          for (int r = 0; r < 4; ++r) stf[(rloc + r) * 132 + col] = acc[mi][ni][r];
        }
      }
    }
    __syncthreads();
#pragma unroll
    for (int i = 0; i < 8; ++i) {
      const int g = (i << 8) + tid;           // 2048 granules: 64 rows x 32 segs
      const int row = g >> 5, seg = g & 31;
      const float4 v = *(const float4*)&stf[row * 132 + (seg << 2)];
      *(float4*)&out[(size_t)(m0 + (pass << 6) + row) * ND + n0 + (seg << 2)] = v;
    }
  }
}

// ---------------------------------------------------------------------------
extern "C" void kernel_launch(void* const* d_in, const int* in_sizes, int n_in,
                              void* d_out, int out_size, void* d_ws,
                              size_t ws_size, hipStream_t stream) {
  const float* x = (const float*)d_in[0];
  const float* Wq = (const float*)d_in[1];
  const float* Wk = (const float*)d_in[2];
  const float* Wv = (const float*)d_in[3];
  const float* Wo = (const float*)d_in[4];
  const int* pos = (const int*)d_in[5];
  float* out = (float*)d_out;

  // workspace layout (bf16 elements)
  bf16* xb = (bf16*)d_ws;                        // 8M  (B,S,D) converted x
  bf16* Wqb = xb + (size_t)NM * ND;              // 1M
  bf16* Wkb = Wqb + (size_t)ND * ND;             // 1M
  bf16* Wvb = Wkb + (size_t)ND * ND;             // 1M
  bf16* Wob = Wvb + (size_t)ND * ND;             // 1M
  bf16* Qw = Wob + (size_t)ND * ND;              // 8M (B,H,S,DK)
  bf16* Kw = Qw + (size_t)NM * NDK * NH;         // 8M (B,H,S,DK)
  bf16* Vw = Kw + (size_t)NM * NDK * NH;         // 8M (B,H,DK,S) transposed
  bf16* Aw = xb;                                 // overlay: x dead after qkv

  conv_kernel<<<6144, 256, 0, stream>>>(x, Wq, Wk, Wv, Wo, xb, Wqb, Wkb, Wvb, Wob);
  qkv_kernel<<<dim3(24, 64), 256, 0, stream>>>(xb, Wqb, Wkb, Wvb, pos, Qw, Kw, Vw);
  attn_kernel<<<dim3(8, 64), 512, 0, stream>>>(Qw, Kw, Vw, Aw);
  oproj_kernel<<<dim3(8, 64), 256, 0, stream>>>(Aw, Wob, out);
}

// Round 7
// 576.243 us; speedup vs baseline: 1.5219x; 1.5219x over previous
//
#include <hip/hip_runtime.h>
#include <hip/hip_bf16.h>

typedef __hip_bfloat16 bf16;
typedef __attribute__((ext_vector_type(8))) short bf16x8;   // 8 bf16 = 4 VGPR (MFMA A/B frag)
typedef __attribute__((ext_vector_type(4))) float f32x4;    // MFMA C/D frag
typedef __attribute__((ext_vector_type(8))) unsigned short us8;

#define NB 4
#define NS 2048
#define ND 1024
#define NH 16
#define NDK 64
#define NM (NB * NS)   // 8192

// async global->LDS, 16B per lane; LDS dest is wave-uniform base + lane*16
__device__ __forceinline__ void async16(const bf16* g, bf16* l) {
  __builtin_amdgcn_global_load_lds(
      (const __attribute__((address_space(1))) void*)g,
      (__attribute__((address_space(3))) void*)l, 16, 0, 0);
}

// ---------------------------------------------------------------------------
// Kernel 0: f32 -> bf16 conversion of x and the 4 weight matrices.
// ---------------------------------------------------------------------------
__global__ __launch_bounds__(256) void conv_kernel(
    const float* __restrict__ x, const float* __restrict__ wq,
    const float* __restrict__ wk, const float* __restrict__ wv,
    const float* __restrict__ wo, bf16* __restrict__ xb,
    bf16* __restrict__ qb, bf16* __restrict__ kb, bf16* __restrict__ vb,
    bf16* __restrict__ ob) {
  const int bid = blockIdx.x;
  const float* src;
  bf16* dst;
  int base;
  if (bid < 4096) {
    src = x; dst = xb; base = bid;
  } else {
    const int t = bid - 4096;
    const int w = t >> 9;
    base = t & 511;
    src = (w == 0) ? wq : (w == 1) ? wk : (w == 2) ? wv : wo;
    dst = (w == 0) ? qb : (w == 1) ? kb : (w == 2) ? vb : ob;
  }
  const size_t off = (size_t)base * 2048 + (size_t)threadIdx.x * 8;
  const float4 a = *(const float4*)(src + off);
  const float4 b = *(const float4*)(src + off + 4);
  us8 pk;
  float va[8] = {a.x, a.y, a.z, a.w, b.x, b.y, b.z, b.w};
#pragma unroll
  for (int i = 0; i < 8; ++i) {
    bf16 h = __float2bfloat16(va[i]);
    pk[i] = *(unsigned short*)&h;
  }
  *(us8*)(dst + off) = pk;
}

// ---------------------------------------------------------------------------
// Kernel 1: fused QKV projection + RoPE.  Y = x @ W^T.
// grid (24, 64): x = which*8 + ntile, y = mtile.  128x128 tile, BK=64, 4 waves.
// Q is additionally scaled by 1/sqrt(DK) (folded from attention).
// Epilogue stages the tile in LDS and writes coalesced 16B stores.
// ---------------------------------------------------------------------------
__global__ __launch_bounds__(256, 2) void qkv_kernel(
    const bf16* __restrict__ x, const bf16* __restrict__ Wq,
    const bf16* __restrict__ Wk, const bf16* __restrict__ Wv,
    const int* __restrict__ pos, bf16* __restrict__ Qo, bf16* __restrict__ Ko,
    bf16* __restrict__ Vo) {
  const int tid = threadIdx.x;
  const int wid = tid >> 6, lane = tid & 63;
  const int lr = lane & 15;              // frag row/col
  const int lk = (lane >> 4) << 3;       // frag k offset
  const int wm = wid >> 1, wn = wid & 1; // 2x2 wave grid
  const int m0 = blockIdx.y << 7;
  const int which = blockIdx.x >> 3;     // 0=Q 1=K 2=V
  const int n0 = (blockIdx.x & 7) << 7;  // feature tile within the 1024
  const bf16* W = (which == 0) ? Wq : (which == 1) ? Wk : Wv;

  __shared__ __align__(16) unsigned char smem_raw[128 * 136 * 2];  // 34816 B
  bf16* sA = (bf16*)smem_raw;              // [128][64] main-loop A
  bf16* sB = (bf16*)(smem_raw + 16384);    // [128][64] main-loop B

  f32x4 acc[4][4];
#pragma unroll
  for (int i = 0; i < 4; ++i)
#pragma unroll
    for (int j = 0; j < 4; ++j) acc[i][j] = (f32x4){0.f, 0.f, 0.f, 0.f};

  const int srow = lane >> 3;        // 0..7
  const int scol = (lane & 7) << 3;  // 0..56

  for (int k0 = 0; k0 < ND; k0 += 64) {
    __syncthreads();
#pragma unroll
    for (int c = 0; c < 4; ++c) {
      const int chunk = (wid << 2) + c;      // 0..15
      const int row = (chunk << 3) + srow;   // 0..127
      async16(x + (size_t)(m0 + row) * ND + k0 + scol, &sA[chunk << 9]);
      async16(W + (size_t)(n0 + row) * ND + k0 + scol, &sB[chunk << 9]);
    }
    __syncthreads();
#pragma unroll
    for (int ks = 0; ks < 2; ++ks) {
      bf16x8 af[4], bfr[4];
#pragma unroll
      for (int mi = 0; mi < 4; ++mi)
        af[mi] = *(const bf16x8*)&sA[((wm << 6) + (mi << 4) + lr) * 64 + (ks << 5) + lk];
#pragma unroll
      for (int ni = 0; ni < 4; ++ni)
        bfr[ni] = *(const bf16x8*)&sB[((wn << 6) + (ni << 4) + lr) * 64 + (ks << 5) + lk];
#pragma unroll
      for (int mi = 0; mi < 4; ++mi)
#pragma unroll
        for (int ni = 0; ni < 4; ++ni)
          acc[mi][ni] = __builtin_amdgcn_mfma_f32_16x16x32_bf16(af[mi], bfr[ni], acc[mi][ni], 0, 0, 0);
    }
  }

  // ---- epilogue: RoPE in-register -> LDS stage -> coalesced 16B stores ----
  const int rbase = (lane >> 4) << 2;  // C/D: row=(lane>>4)*4+r, col=lane&15
  const int b = m0 >> 11;              // single batch per block (128 | 2048)
  const int s0g = m0 & (NS - 1);
  const int h0 = n0 >> 6;              // two heads per 128-col tile
  const float oscale = (which == 0) ? 0.125f : 1.0f;  // 1/sqrt(64) into Q

  __syncthreads();                     // all sA/sB reads done before overwrite
  bf16* st = (bf16*)smem_raw;          // [128][136] stage

  if (which == 2) {
    // V: stage TRANSPOSED [dkfull 0..127][srow 0..127]
#pragma unroll
    for (int mi = 0; mi < 4; ++mi) {
      const int sr = (wm << 6) + (mi << 4) + rbase;
#pragma unroll
      for (int ni = 0; ni < 4; ++ni) {
        const int dkfull = (wn << 6) + (ni << 4) + lr;
#pragma unroll
        for (int r = 0; r < 4; ++r)
          st[dkfull * 136 + sr + r] = __float2bfloat16(acc[mi][ni][r]);
      }
    }
  } else {
#pragma unroll
    for (int mi = 0; mi < 4; ++mi) {
      const int sr = (wm << 6) + (mi << 4) + rbase;
#pragma unroll
      for (int ni = 0; ni < 4; ++ni) {
        const int col = (wn << 6) + (ni << 4) + lr;  // 0..127
        const int dk = col & 63;
        // inv_freq = 10000^(-(dk/2)/32) = 2^(-(dk/2)*log2(1e4)/32)
        const float invf = exp2f(-(float)(dk >> 1) * 0.4152410118609203f);
#pragma unroll
        for (int r = 0; r < 4; ++r) {
          float v = acc[mi][ni][r];
          float other = __shfl_xor(v, 1);  // partner column (dk^1)
          const int s = s0g + sr + r;
          float ang = (float)pos[s] * invf;
          float sn, cn;
          sincosf(ang, &sn, &cn);
          float res = (dk & 1) ? fmaf(other, sn, v * cn) : fmaf(v, cn, -(other * sn));
          st[(sr + r) * 136 + col] = __float2bfloat16(res * oscale);
        }
      }
    }
  }
  __syncthreads();

  if (which == 2) {
    // write V^T (bh, dk, s): 2 planes x 64 dk-rows x 256B contiguous
#pragma unroll
    for (int i = 0; i < 8; ++i) {
      const int g = (i << 8) + tid;
      const int plane = g >> 10, dkr = (g >> 4) & 63, seg = g & 15;
      us8 v = *(const us8*)&st[(plane * 64 + dkr) * 136 + (seg << 3)];
      *(us8*)&Vo[((size_t)(b * NH + h0 + plane) * NDK + dkr) * NS + s0g + (seg << 3)] = v;
    }
  } else {
    bf16* dst = (which == 0) ? Qo : Ko;
    // write (bh, s, dk): 2 planes x 128 s-rows x 128B contiguous
#pragma unroll
    for (int i = 0; i < 8; ++i) {
      const int g = (i << 8) + tid;
      const int plane = g >> 10, row = (g >> 3) & 127, seg = g & 7;
      us8 v = *(const us8*)&st[row * 136 + (plane << 6) + (seg << 3)];
      *(us8*)&dst[((size_t)(b * NH + h0 + plane) * NS + s0g + row) * NDK + (seg << 3)] = v;
    }
  }
}

// ---------------------------------------------------------------------------
// Kernel 2: causal flash attention.
// grid (8, 64), 256 threads (4 waves), launch_bounds(256,2) -> VGPR cap 128
// (round-5 regime: 88 VGPR, no spills).  512 blocks = 2 resident blocks/CU.
// Each wave runs TWO sequential phases: 32 q-rows of tile x, then 32 q-rows
// of tile 15-x  => per-wave work constant (causal pairing), all CUs equal.
// K/V frag loads are JIT (latency hidden by 16 waves/CU TLP).
// Row-sum via ones-MFMA; 1/sqrt(dk) pre-folded into Q.  No barriers.
// ---------------------------------------------------------------------------
__global__ __launch_bounds__(256, 2) void attn_kernel(
    const bf16* __restrict__ Q, const bf16* __restrict__ K,
    const bf16* __restrict__ V, bf16* __restrict__ O) {
  const int tid = threadIdx.x;
  const int wid = tid >> 6, lane = tid & 63;
  const int lr = lane & 15, lk = (lane >> 4) << 3;
  const int rbase = (lane >> 4) << 2;
  const int bh = blockIdx.y;

  const bf16* Qb = Q + (size_t)bh * NS * NDK;
  const bf16* Kb = K + (size_t)bh * NS * NDK;
  const bf16* Vb = V + (size_t)bh * NS * NDK;  // [64][2048]
  bf16* Ob = O + (size_t)bh * NS * NDK;

  __shared__ bf16 sP[4][32 * 72];  // per-wave P buffer, stride 72 (16B mult)
  bf16* Pw = &sP[wid][0];

  bf16x8 ones;
#pragma unroll
  for (int i = 0; i < 8; ++i) ones[i] = (short)0x3F80;  // bf16 1.0

  const float L2E = 1.44269504f;

#pragma unroll 1
  for (int phase = 0; phase < 2; ++phase) {
    const int qt = (phase == 0) ? blockIdx.x : (15 - blockIdx.x);
    const int qw = (qt << 7) + (wid << 5);  // wave's q base (32 rows)

    bf16x8 qf[2][2];
#pragma unroll
    for (int mi = 0; mi < 2; ++mi)
#pragma unroll
      for (int ks = 0; ks < 2; ++ks)
        qf[mi][ks] = *(const bf16x8*)&Qb[(size_t)(qw + (mi << 4) + lr) * NDK + (ks << 5) + lk];

    f32x4 o[2][4];
    float mrun[2][4], lrun[2][4];
#pragma unroll
    for (int mi = 0; mi < 2; ++mi)
#pragma unroll
      for (int j = 0; j < 4; ++j) {
        o[mi][j] = (f32x4){0.f, 0.f, 0.f, 0.f};
        mrun[mi][j] = -1e30f;
        lrun[mi][j] = 0.f;
      }

    const int ntiles = ((qw + 31) >> 6) + 1;

#pragma unroll 1
    for (int t = 0; t < ntiles; ++t) {
      const int kv0 = t << 6;
      // ---- QK^T (K frags JIT) ----
      f32x4 sc[2][4];
#pragma unroll
      for (int mi = 0; mi < 2; ++mi)
#pragma unroll
        for (int nj = 0; nj < 4; ++nj) sc[mi][nj] = (f32x4){0.f, 0.f, 0.f, 0.f};
      {
        bf16x8 kf[4][2];
#pragma unroll
        for (int nj = 0; nj < 4; ++nj)
#pragma unroll
          for (int ks = 0; ks < 2; ++ks)
            kf[nj][ks] = *(const bf16x8*)&Kb[(size_t)(kv0 + (nj << 4) + lr) * NDK + (ks << 5) + lk];
#pragma unroll
        for (int ks = 0; ks < 2; ++ks)
#pragma unroll
          for (int nj = 0; nj < 4; ++nj)
#pragma unroll
            for (int mi = 0; mi < 2; ++mi)
              sc[mi][nj] = __builtin_amdgcn_mfma_f32_16x16x32_bf16(qf[mi][ks], kf[nj][ks], sc[mi][nj], 0, 0, 0);
      }

      // ---- mask (last tile only) + row max ----
      float mnew[2][4];
#pragma unroll
      for (int mi = 0; mi < 2; ++mi)
#pragma unroll
        for (int r = 0; r < 4; ++r) mnew[mi][r] = mrun[mi][r];
      if (t == ntiles - 1) {
#pragma unroll
        for (int mi = 0; mi < 2; ++mi)
#pragma unroll
          for (int nj = 0; nj < 4; ++nj) {
            const int col = kv0 + (nj << 4) + lr;
#pragma unroll
            for (int r = 0; r < 4; ++r) {
              const int row = qw + (mi << 4) + rbase + r;
              float s = sc[mi][nj][r];
              if (col > row) s = -1e30f;
              sc[mi][nj][r] = s;
              mnew[mi][r] = fmaxf(mnew[mi][r], s);
            }
          }
      } else {
#pragma unroll
        for (int mi = 0; mi < 2; ++mi)
#pragma unroll
          for (int nj = 0; nj < 4; ++nj)
#pragma unroll
            for (int r = 0; r < 4; ++r)
              mnew[mi][r] = fmaxf(mnew[mi][r], sc[mi][nj][r]);
      }
      float alf[2][4];
#pragma unroll
      for (int mi = 0; mi < 2; ++mi)
#pragma unroll
        for (int r = 0; r < 4; ++r) {
          float v = mnew[mi][r];
          v = fmaxf(v, __shfl_xor(v, 1));
          v = fmaxf(v, __shfl_xor(v, 2));
          v = fmaxf(v, __shfl_xor(v, 4));
          v = fmaxf(v, __shfl_xor(v, 8));
          alf[mi][r] = exp2f((mrun[mi][r] - v) * L2E);
          mrun[mi][r] = v;
#pragma unroll
          for (int dj = 0; dj < 4; ++dj) o[mi][dj][r] *= alf[mi][r];
        }

      // ---- exp + P -> LDS (bf16, C-layout scatter) ----
#pragma unroll
      for (int mi = 0; mi < 2; ++mi)
#pragma unroll
        for (int nj = 0; nj < 4; ++nj)
#pragma unroll
          for (int r = 0; r < 4; ++r) {
            float e = exp2f((sc[mi][nj][r] - mrun[mi][r]) * L2E);
            Pw[((mi << 4) + rbase + r) * 72 + (nj << 4) + lr] = __float2bfloat16(e);
          }

      // ---- P read (A-frag) + row-sum via ones-MFMA + PV (V frags JIT) ----
      bf16x8 pa[2][2];
#pragma unroll
      for (int mi = 0; mi < 2; ++mi)
#pragma unroll
        for (int ks = 0; ks < 2; ++ks)
          pa[mi][ks] = *(const bf16x8*)&Pw[((mi << 4) + lr) * 72 + (ks << 5) + lk];

#pragma unroll
      for (int mi = 0; mi < 2; ++mi) {
        f32x4 ls = (f32x4){0.f, 0.f, 0.f, 0.f};
        ls = __builtin_amdgcn_mfma_f32_16x16x32_bf16(pa[mi][0], ones, ls, 0, 0, 0);
        ls = __builtin_amdgcn_mfma_f32_16x16x32_bf16(pa[mi][1], ones, ls, 0, 0, 0);
#pragma unroll
        for (int r = 0; r < 4; ++r)
          lrun[mi][r] = fmaf(lrun[mi][r], alf[mi][r], ls[r]);
      }

      {
        bf16x8 vf[4][2];
#pragma unroll
        for (int dj = 0; dj < 4; ++dj)
#pragma unroll
          for (int ks = 0; ks < 2; ++ks)
            vf[dj][ks] = *(const bf16x8*)&Vb[(size_t)((dj << 4) + lr) * NS + kv0 + (ks << 5) + lk];
#pragma unroll
        for (int ks = 0; ks < 2; ++ks)
#pragma unroll
          for (int dj = 0; dj < 4; ++dj)
#pragma unroll
            for (int mi = 0; mi < 2; ++mi)
              o[mi][dj] = __builtin_amdgcn_mfma_f32_16x16x32_bf16(pa[mi][ks], vf[dj][ks], o[mi][dj], 0, 0, 0);
      }
    }

    // ---- epilogue: normalize into Pw (per-wave), coalesced 16B stores ----
#pragma unroll
    for (int mi = 0; mi < 2; ++mi)
#pragma unroll
      for (int r = 0; r < 4; ++r) {
        const float inv = 1.f / lrun[mi][r];
        const int row = (mi << 4) + rbase + r;
#pragma unroll
        for (int dj = 0; dj < 4; ++dj)
          Pw[row * 72 + (dj << 4) + lr] = __float2bfloat16(o[mi][dj][r] * inv);
      }
#pragma unroll
    for (int i = 0; i < 4; ++i) {
      const int g = (i << 6) + lane;          // 256 granules: 32 rows x 8 segs
      const int row = g >> 3, seg = g & 7;
      us8 v = *(const us8*)&Pw[row * 72 + (seg << 3)];
      *(us8*)&Ob[(size_t)(qw + row) * NDK + (seg << 3)] = v;
    }
  }
}

// ---------------------------------------------------------------------------
// Kernel 3: output projection.  out = attnO @ Wo^T (f32 out).  grid (8, 64).
// Epilogue: two-pass LDS staging, float4 coalesced stores.
// ---------------------------------------------------------------------------
__global__ __launch_bounds__(256, 2) void oproj_kernel(
    const bf16* __restrict__ AO, const bf16* __restrict__ Wo,
    float* __restrict__ out) {
  const int tid = threadIdx.x;
  const int wid = tid >> 6, lane = tid & 63;
  const int lr = lane & 15, lk = (lane >> 4) << 3;
  const int wm = wid >> 1, wn = wid & 1;
  const int m0 = blockIdx.y << 7;
  const int n0 = blockIdx.x << 7;

  __shared__ __align__(16) unsigned char smem_raw[64 * 132 * 4];  // 33792 B
  bf16* sA = (bf16*)smem_raw;
  bf16* sB = (bf16*)(smem_raw + 16384);

  f32x4 acc[4][4];
#pragma unroll
  for (int i = 0; i < 4; ++i)
#pragma unroll
    for (int j = 0; j < 4; ++j) acc[i][j] = (f32x4){0.f, 0.f, 0.f, 0.f};

  const int srow = lane >> 3;
  const int scol = (lane & 7) << 3;

  for (int k0 = 0; k0 < ND; k0 += 64) {
    __syncthreads();
    const int h = k0 >> 6;
#pragma unroll
    for (int c = 0; c < 4; ++c) {
      const int chunk = (wid << 2) + c;
      const int row = (chunk << 3) + srow;
      const int m = m0 + row;
      async16(AO + ((size_t)((m >> 11) * NH + h) * NS + (m & (NS - 1))) * NDK + scol,
              &sA[chunk << 9]);
      async16(Wo + (size_t)(n0 + row) * ND + k0 + scol, &sB[chunk << 9]);
    }
    __syncthreads();
#pragma unroll
    for (int ks = 0; ks < 2; ++ks) {
      bf16x8 af[4], bfr[4];
#pragma unroll
      for (int mi = 0; mi < 4; ++mi)
        af[mi] = *(const bf16x8*)&sA[((wm << 6) + (mi << 4) + lr) * 64 + (ks << 5) + lk];
#pragma unroll
      for (int ni = 0; ni < 4; ++ni)
        bfr[ni] = *(const bf16x8*)&sB[((wn << 6) + (ni << 4) + lr) * 64 + (ks << 5) + lk];
#pragma unroll
      for (int mi = 0; mi < 4; ++mi)
#pragma unroll
        for (int ni = 0; ni < 4; ++ni)
          acc[mi][ni] = __builtin_amdgcn_mfma_f32_16x16x32_bf16(af[mi], bfr[ni], acc[mi][ni], 0, 0, 0);
    }
  }

  // ---- epilogue: two-pass f32 LDS stage + float4 stores ----
  const int rbase = (lane >> 4) << 2;
  float* stf = (float*)smem_raw;  // [64][132]
#pragma unroll
  for (int pass = 0; pass < 2; ++pass) {
    __syncthreads();
    if (wm == pass) {
#pragma unroll
      for (int mi = 0; mi < 4; ++mi) {
        const int rloc = (mi << 4) + rbase;  // 0..63 within half-tile
#pragma unroll
        for (int ni = 0; ni < 4; ++ni) {
          const int col = (wn << 6) + (ni << 4) + lr;
#pragma unroll
          for (int r = 0; r < 4; ++r) stf[(rloc + r) * 132 + col] = acc[mi][ni][r];
        }
      }
    }
    __syncthreads();
#pragma unroll
    for (int i = 0; i < 8; ++i) {
      const int g = (i << 8) + tid;           // 2048 granules: 64 rows x 32 segs
      const int row = g >> 5, seg = g & 31;
      const float4 v = *(const float4*)&stf[row * 132 + (seg << 2)];
      *(float4*)&out[(size_t)(m0 + (pass << 6) + row) * ND + n0 + (seg << 2)] = v;
    }
  }
}

// ---------------------------------------------------------------------------
extern "C" void kernel_launch(void* const* d_in, const int* in_sizes, int n_in,
                              void* d_out, int out_size, void* d_ws,
                              size_t ws_size, hipStream_t stream) {
  const float* x = (const float*)d_in[0];
  const float* Wq = (const float*)d_in[1];
  const float* Wk = (const float*)d_in[2];
  const float* Wv = (const float*)d_in[3];
  const float* Wo = (const float*)d_in[4];
  const int* pos = (const int*)d_in[5];
  float* out = (float*)d_out;

  // workspace layout (bf16 elements)
  bf16* xb = (bf16*)d_ws;                        // 8M  (B,S,D) converted x
  bf16* Wqb = xb + (size_t)NM * ND;              // 1M
  bf16* Wkb = Wqb + (size_t)ND * ND;             // 1M
  bf16* Wvb = Wkb + (size_t)ND * ND;             // 1M
  bf16* Wob = Wvb + (size_t)ND * ND;             // 1M
  bf16* Qw = Wob + (size_t)ND * ND;              // 8M (B,H,S,DK)
  bf16* Kw = Qw + (size_t)NM * NDK * NH;         // 8M (B,H,S,DK)
  bf16* Vw = Kw + (size_t)NM * NDK * NH;         // 8M (B,H,DK,S) transposed
  bf16* Aw = xb;                                 // overlay: x dead after qkv

  conv_kernel<<<6144, 256, 0, stream>>>(x, Wq, Wk, Wv, Wo, xb, Wqb, Wkb, Wvb, Wob);
  qkv_kernel<<<dim3(24, 64), 256, 0, stream>>>(xb, Wqb, Wkb, Wvb, pos, Qw, Kw, Vw);
  attn_kernel<<<dim3(8, 64), 256, 0, stream>>>(Qw, Kw, Vw, Aw);
  oproj_kernel<<<dim3(8, 64), 256, 0, stream>>>(Aw, Wob, out);
}

// Round 8
// 355.264 us; speedup vs baseline: 2.4685x; 1.6220x over previous
//
#include <hip/hip_runtime.h>
#include <hip/hip_bf16.h>

typedef __hip_bfloat16 bf16;
typedef __attribute__((ext_vector_type(8))) short bf16x8;   // 8 bf16 = 4 VGPR (MFMA A/B frag)
typedef __attribute__((ext_vector_type(4))) float f32x4;    // MFMA C/D frag
typedef __attribute__((ext_vector_type(8))) unsigned short us8;

#define NB 4
#define NS 2048
#define ND 1024
#define NH 16
#define NDK 64
#define NM (NB * NS)   // 8192

// async global->LDS, 16B per lane; LDS dest is wave-uniform base + lane*16
__device__ __forceinline__ void async16(const bf16* g, bf16* l) {
  __builtin_amdgcn_global_load_lds(
      (const __attribute__((address_space(1))) void*)g,
      (__attribute__((address_space(3))) void*)l, 16, 0, 0);
}

// ---------------------------------------------------------------------------
// Kernel 0: f32 -> bf16 conversion of x and the 4 weight matrices.
// ---------------------------------------------------------------------------
__global__ __launch_bounds__(256) void conv_kernel(
    const float* __restrict__ x, const float* __restrict__ wq,
    const float* __restrict__ wk, const float* __restrict__ wv,
    const float* __restrict__ wo, bf16* __restrict__ xb,
    bf16* __restrict__ qb, bf16* __restrict__ kb, bf16* __restrict__ vb,
    bf16* __restrict__ ob) {
  const int bid = blockIdx.x;
  const float* src;
  bf16* dst;
  int base;
  if (bid < 4096) {
    src = x; dst = xb; base = bid;
  } else {
    const int t = bid - 4096;
    const int w = t >> 9;
    base = t & 511;
    src = (w == 0) ? wq : (w == 1) ? wk : (w == 2) ? wv : wo;
    dst = (w == 0) ? qb : (w == 1) ? kb : (w == 2) ? vb : ob;
  }
  const size_t off = (size_t)base * 2048 + (size_t)threadIdx.x * 8;
  const float4 a = *(const float4*)(src + off);
  const float4 b = *(const float4*)(src + off + 4);
  us8 pk;
  float va[8] = {a.x, a.y, a.z, a.w, b.x, b.y, b.z, b.w};
#pragma unroll
  for (int i = 0; i < 8; ++i) {
    bf16 h = __float2bfloat16(va[i]);
    pk[i] = *(unsigned short*)&h;
  }
  *(us8*)(dst + off) = pk;
}

// ---------------------------------------------------------------------------
// Kernel 1: fused QKV projection + RoPE.  Y = x @ W^T.
// grid (24, 64): x = which*8 + ntile, y = mtile.  128x128 tile, BK=64, 4 waves.
// Q is additionally scaled by 1/sqrt(DK) (folded from attention).
// RoPE trig via native __sinf/__cosf (NO libm call -> no scratch spill of acc).
// Epilogue stages the tile in LDS and writes coalesced 16B stores.
// ---------------------------------------------------------------------------
__global__ __launch_bounds__(256, 2) void qkv_kernel(
    const bf16* __restrict__ x, const bf16* __restrict__ Wq,
    const bf16* __restrict__ Wk, const bf16* __restrict__ Wv,
    const int* __restrict__ pos, bf16* __restrict__ Qo, bf16* __restrict__ Ko,
    bf16* __restrict__ Vo) {
  const int tid = threadIdx.x;
  const int wid = tid >> 6, lane = tid & 63;
  const int lr = lane & 15;              // frag row/col
  const int lk = (lane >> 4) << 3;       // frag k offset
  const int wm = wid >> 1, wn = wid & 1; // 2x2 wave grid
  const int m0 = blockIdx.y << 7;
  const int which = blockIdx.x >> 3;     // 0=Q 1=K 2=V
  const int n0 = (blockIdx.x & 7) << 7;  // feature tile within the 1024
  const bf16* W = (which == 0) ? Wq : (which == 1) ? Wk : Wv;

  __shared__ __align__(16) unsigned char smem_raw[128 * 136 * 2];  // 34816 B
  bf16* sA = (bf16*)smem_raw;              // [128][64] main-loop A
  bf16* sB = (bf16*)(smem_raw + 16384);    // [128][64] main-loop B

  f32x4 acc[4][4];
#pragma unroll
  for (int i = 0; i < 4; ++i)
#pragma unroll
    for (int j = 0; j < 4; ++j) acc[i][j] = (f32x4){0.f, 0.f, 0.f, 0.f};

  const int srow = lane >> 3;        // 0..7
  const int scol = (lane & 7) << 3;  // 0..56

  for (int k0 = 0; k0 < ND; k0 += 64) {
    __syncthreads();
#pragma unroll
    for (int c = 0; c < 4; ++c) {
      const int chunk = (wid << 2) + c;      // 0..15
      const int row = (chunk << 3) + srow;   // 0..127
      async16(x + (size_t)(m0 + row) * ND + k0 + scol, &sA[chunk << 9]);
      async16(W + (size_t)(n0 + row) * ND + k0 + scol, &sB[chunk << 9]);
    }
    __syncthreads();
#pragma unroll
    for (int ks = 0; ks < 2; ++ks) {
      bf16x8 af[4], bfr[4];
#pragma unroll
      for (int mi = 0; mi < 4; ++mi)
        af[mi] = *(const bf16x8*)&sA[((wm << 6) + (mi << 4) + lr) * 64 + (ks << 5) + lk];
#pragma unroll
      for (int ni = 0; ni < 4; ++ni)
        bfr[ni] = *(const bf16x8*)&sB[((wn << 6) + (ni << 4) + lr) * 64 + (ks << 5) + lk];
#pragma unroll
      for (int mi = 0; mi < 4; ++mi)
#pragma unroll
        for (int ni = 0; ni < 4; ++ni)
          acc[mi][ni] = __builtin_amdgcn_mfma_f32_16x16x32_bf16(af[mi], bfr[ni], acc[mi][ni], 0, 0, 0);
    }
  }

  // ---- epilogue: RoPE in-register -> LDS stage -> coalesced 16B stores ----
  const int rbase = (lane >> 4) << 2;  // C/D: row=(lane>>4)*4+r, col=lane&15
  const int b = m0 >> 11;              // single batch per block (128 | 2048)
  const int s0g = m0 & (NS - 1);
  const int h0 = n0 >> 6;              // two heads per 128-col tile
  const float oscale = (which == 0) ? 0.125f : 1.0f;  // 1/sqrt(64) into Q

  __syncthreads();                     // all sA/sB reads done before overwrite
  bf16* st = (bf16*)smem_raw;          // [128][136] stage

  if (which == 2) {
    // V: stage TRANSPOSED [dkfull 0..127][srow 0..127]
#pragma unroll
    for (int mi = 0; mi < 4; ++mi) {
      const int sr = (wm << 6) + (mi << 4) + rbase;
#pragma unroll
      for (int ni = 0; ni < 4; ++ni) {
        const int dkfull = (wn << 6) + (ni << 4) + lr;
#pragma unroll
        for (int r = 0; r < 4; ++r)
          st[dkfull * 136 + sr + r] = __float2bfloat16(acc[mi][ni][r]);
      }
    }
  } else {
#pragma unroll
    for (int mi = 0; mi < 4; ++mi) {
      const int sr = (wm << 6) + (mi << 4) + rbase;
#pragma unroll
      for (int ni = 0; ni < 4; ++ni) {
        const int col = (wn << 6) + (ni << 4) + lr;  // 0..127
        const int dk = col & 63;
        // inv_freq = 10000^(-(dk/2)/32) = 2^(-(dk/2)*log2(1e4)/32)
        const float invf = exp2f(-(float)(dk >> 1) * 0.4152410118609203f);
#pragma unroll
        for (int r = 0; r < 4; ++r) {
          float v = acc[mi][ni][r];
          float other = __shfl_xor(v, 1);  // partner column (dk^1)
          const int s = s0g + sr + r;
          float ang = (float)pos[s] * invf;
          float sn = __sinf(ang);          // native v_sin_f32 (inline, no call)
          float cn = __cosf(ang);          // native v_cos_f32
          float res = (dk & 1) ? fmaf(other, sn, v * cn) : fmaf(v, cn, -(other * sn));
          st[(sr + r) * 136 + col] = __float2bfloat16(res * oscale);
        }
      }
    }
  }
  __syncthreads();

  if (which == 2) {
    // write V^T (bh, dk, s): 2 planes x 64 dk-rows x 256B contiguous
#pragma unroll
    for (int i = 0; i < 8; ++i) {
      const int g = (i << 8) + tid;
      const int plane = g >> 10, dkr = (g >> 4) & 63, seg = g & 15;
      us8 v = *(const us8*)&st[(plane * 64 + dkr) * 136 + (seg << 3)];
      *(us8*)&Vo[((size_t)(b * NH + h0 + plane) * NDK + dkr) * NS + s0g + (seg << 3)] = v;
    }
  } else {
    bf16* dst = (which == 0) ? Qo : Ko;
    // write (bh, s, dk): 2 planes x 128 s-rows x 128B contiguous
#pragma unroll
    for (int i = 0; i < 8; ++i) {
      const int g = (i << 8) + tid;
      const int plane = g >> 10, row = (g >> 3) & 127, seg = g & 7;
      us8 v = *(const us8*)&st[row * 136 + (plane << 6) + (seg << 3)];
      *(us8*)&dst[((size_t)(b * NH + h0 + plane) * NS + s0g + row) * NDK + (seg << 3)] = v;
    }
  }
}

// ---------------------------------------------------------------------------
// Kernel 2: causal flash attention.
// grid (8, 64), 256 threads (4 waves), launch_bounds(256,2) -> VGPR cap 128
// (measured 88 VGPR, no spills).  512 blocks = 2 resident blocks/CU.
// Each wave runs TWO sequential phases: 32 q-rows of tile x, then 32 q-rows
// of tile 15-x  => per-wave work constant (causal pairing), all CUs equal.
// K/V frag loads are JIT (latency hidden by 16 waves/CU TLP).
// Row-sum via ones-MFMA; 1/sqrt(dk) pre-folded into Q.  No barriers.
// ---------------------------------------------------------------------------
__global__ __launch_bounds__(256, 2) void attn_kernel(
    const bf16* __restrict__ Q, const bf16* __restrict__ K,
    const bf16* __restrict__ V, bf16* __restrict__ O) {
  const int tid = threadIdx.x;
  const int wid = tid >> 6, lane = tid & 63;
  const int lr = lane & 15, lk = (lane >> 4) << 3;
  const int rbase = (lane >> 4) << 2;
  const int bh = blockIdx.y;

  const bf16* Qb = Q + (size_t)bh * NS * NDK;
  const bf16* Kb = K + (size_t)bh * NS * NDK;
  const bf16* Vb = V + (size_t)bh * NS * NDK;  // [64][2048]
  bf16* Ob = O + (size_t)bh * NS * NDK;

  __shared__ bf16 sP[4][32 * 72];  // per-wave P buffer, stride 72 (16B mult)
  bf16* Pw = &sP[wid][0];

  bf16x8 ones;
#pragma unroll
  for (int i = 0; i < 8; ++i) ones[i] = (short)0x3F80;  // bf16 1.0

  const float L2E = 1.44269504f;

#pragma unroll 1
  for (int phase = 0; phase < 2; ++phase) {
    const int qt = (phase == 0) ? blockIdx.x : (15 - blockIdx.x);
    const int qw = (qt << 7) + (wid << 5);  // wave's q base (32 rows)

    bf16x8 qf[2][2];
#pragma unroll
    for (int mi = 0; mi < 2; ++mi)
#pragma unroll
      for (int ks = 0; ks < 2; ++ks)
        qf[mi][ks] = *(const bf16x8*)&Qb[(size_t)(qw + (mi << 4) + lr) * NDK + (ks << 5) + lk];

    f32x4 o[2][4];
    float mrun[2][4], lrun[2][4];
#pragma unroll
    for (int mi = 0; mi < 2; ++mi)
#pragma unroll
      for (int j = 0; j < 4; ++j) {
        o[mi][j] = (f32x4){0.f, 0.f, 0.f, 0.f};
        mrun[mi][j] = -1e30f;
        lrun[mi][j] = 0.f;
      }

    const int ntiles = ((qw + 31) >> 6) + 1;

#pragma unroll 1
    for (int t = 0; t < ntiles; ++t) {
      const int kv0 = t << 6;
      // ---- QK^T (K frags JIT) ----
      f32x4 sc[2][4];
#pragma unroll
      for (int mi = 0; mi < 2; ++mi)
#pragma unroll
        for (int nj = 0; nj < 4; ++nj) sc[mi][nj] = (f32x4){0.f, 0.f, 0.f, 0.f};
      {
        bf16x8 kf[4][2];
#pragma unroll
        for (int nj = 0; nj < 4; ++nj)
#pragma unroll
          for (int ks = 0; ks < 2; ++ks)
            kf[nj][ks] = *(const bf16x8*)&Kb[(size_t)(kv0 + (nj << 4) + lr) * NDK + (ks << 5) + lk];
#pragma unroll
        for (int ks = 0; ks < 2; ++ks)
#pragma unroll
          for (int nj = 0; nj < 4; ++nj)
#pragma unroll
            for (int mi = 0; mi < 2; ++mi)
              sc[mi][nj] = __builtin_amdgcn_mfma_f32_16x16x32_bf16(qf[mi][ks], kf[nj][ks], sc[mi][nj], 0, 0, 0);
      }

      // ---- mask (last tile only) + row max ----
      float mnew[2][4];
#pragma unroll
      for (int mi = 0; mi < 2; ++mi)
#pragma unroll
        for (int r = 0; r < 4; ++r) mnew[mi][r] = mrun[mi][r];
      if (t == ntiles - 1) {
#pragma unroll
        for (int mi = 0; mi < 2; ++mi)
#pragma unroll
          for (int nj = 0; nj < 4; ++nj) {
            const int col = kv0 + (nj << 4) + lr;
#pragma unroll
            for (int r = 0; r < 4; ++r) {
              const int row = qw + (mi << 4) + rbase + r;
              float s = sc[mi][nj][r];
              if (col > row) s = -1e30f;
              sc[mi][nj][r] = s;
              mnew[mi][r] = fmaxf(mnew[mi][r], s);
            }
          }
      } else {
#pragma unroll
        for (int mi = 0; mi < 2; ++mi)
#pragma unroll
          for (int nj = 0; nj < 4; ++nj)
#pragma unroll
            for (int r = 0; r < 4; ++r)
              mnew[mi][r] = fmaxf(mnew[mi][r], sc[mi][nj][r]);
      }
      float alf[2][4];
#pragma unroll
      for (int mi = 0; mi < 2; ++mi)
#pragma unroll
        for (int r = 0; r < 4; ++r) {
          float v = mnew[mi][r];
          v = fmaxf(v, __shfl_xor(v, 1));
          v = fmaxf(v, __shfl_xor(v, 2));
          v = fmaxf(v, __shfl_xor(v, 4));
          v = fmaxf(v, __shfl_xor(v, 8));
          alf[mi][r] = exp2f((mrun[mi][r] - v) * L2E);
          mrun[mi][r] = v;
#pragma unroll
          for (int dj = 0; dj < 4; ++dj) o[mi][dj][r] *= alf[mi][r];
        }

      // ---- exp + P -> LDS (bf16, C-layout scatter) ----
#pragma unroll
      for (int mi = 0; mi < 2; ++mi)
#pragma unroll
        for (int nj = 0; nj < 4; ++nj)
#pragma unroll
          for (int r = 0; r < 4; ++r) {
            float e = exp2f((sc[mi][nj][r] - mrun[mi][r]) * L2E);
            Pw[((mi << 4) + rbase + r) * 72 + (nj << 4) + lr] = __float2bfloat16(e);
          }

      // ---- P read (A-frag) + row-sum via ones-MFMA + PV (V frags JIT) ----
      bf16x8 pa[2][2];
#pragma unroll
      for (int mi = 0; mi < 2; ++mi)
#pragma unroll
        for (int ks = 0; ks < 2; ++ks)
          pa[mi][ks] = *(const bf16x8*)&Pw[((mi << 4) + lr) * 72 + (ks << 5) + lk];

#pragma unroll
      for (int mi = 0; mi < 2; ++mi) {
        f32x4 ls = (f32x4){0.f, 0.f, 0.f, 0.f};
        ls = __builtin_amdgcn_mfma_f32_16x16x32_bf16(pa[mi][0], ones, ls, 0, 0, 0);
        ls = __builtin_amdgcn_mfma_f32_16x16x32_bf16(pa[mi][1], ones, ls, 0, 0, 0);
#pragma unroll
        for (int r = 0; r < 4; ++r)
          lrun[mi][r] = fmaf(lrun[mi][r], alf[mi][r], ls[r]);
      }

      {
        bf16x8 vf[4][2];
#pragma unroll
        for (int dj = 0; dj < 4; ++dj)
#pragma unroll
          for (int ks = 0; ks < 2; ++ks)
            vf[dj][ks] = *(const bf16x8*)&Vb[(size_t)((dj << 4) + lr) * NS + kv0 + (ks << 5) + lk];
#pragma unroll
        for (int ks = 0; ks < 2; ++ks)
#pragma unroll
          for (int dj = 0; dj < 4; ++dj)
#pragma unroll
            for (int mi = 0; mi < 2; ++mi)
              o[mi][dj] = __builtin_amdgcn_mfma_f32_16x16x32_bf16(pa[mi][ks], vf[dj][ks], o[mi][dj], 0, 0, 0);
      }
    }

    // ---- epilogue: normalize into Pw (per-wave), coalesced 16B stores ----
#pragma unroll
    for (int mi = 0; mi < 2; ++mi)
#pragma unroll
      for (int r = 0; r < 4; ++r) {
        const float inv = 1.f / lrun[mi][r];
        const int row = (mi << 4) + rbase + r;
#pragma unroll
        for (int dj = 0; dj < 4; ++dj)
          Pw[row * 72 + (dj << 4) + lr] = __float2bfloat16(o[mi][dj][r] * inv);
      }
#pragma unroll
    for (int i = 0; i < 4; ++i) {
      const int g = (i << 6) + lane;          // 256 granules: 32 rows x 8 segs
      const int row = g >> 3, seg = g & 7;
      us8 v = *(const us8*)&Pw[row * 72 + (seg << 3)];
      *(us8*)&Ob[(size_t)(qw + row) * NDK + (seg << 3)] = v;
    }
  }
}

// ---------------------------------------------------------------------------
// Kernel 3: output projection.  out = attnO @ Wo^T (f32 out).  grid (8, 64).
// Epilogue: two-pass LDS staging, float4 coalesced stores.
// ---------------------------------------------------------------------------
__global__ __launch_bounds__(256, 2) void oproj_kernel(
    const bf16* __restrict__ AO, const bf16* __restrict__ Wo,
    float* __restrict__ out) {
  const int tid = threadIdx.x;
  const int wid = tid >> 6, lane = tid & 63;
  const int lr = lane & 15, lk = (lane >> 4) << 3;
  const int wm = wid >> 1, wn = wid & 1;
  const int m0 = blockIdx.y << 7;
  const int n0 = blockIdx.x << 7;

  __shared__ __align__(16) unsigned char smem_raw[64 * 132 * 4];  // 33792 B
  bf16* sA = (bf16*)smem_raw;
  bf16* sB = (bf16*)(smem_raw + 16384);

  f32x4 acc[4][4];
#pragma unroll
  for (int i = 0; i < 4; ++i)
#pragma unroll
    for (int j = 0; j < 4; ++j) acc[i][j] = (f32x4){0.f, 0.f, 0.f, 0.f};

  const int srow = lane >> 3;
  const int scol = (lane & 7) << 3;

  for (int k0 = 0; k0 < ND; k0 += 64) {
    __syncthreads();
    const int h = k0 >> 6;
#pragma unroll
    for (int c = 0; c < 4; ++c) {
      const int chunk = (wid << 2) + c;
      const int row = (chunk << 3) + srow;
      const int m = m0 + row;
      async16(AO + ((size_t)((m >> 11) * NH + h) * NS + (m & (NS - 1))) * NDK + scol,
              &sA[chunk << 9]);
      async16(Wo + (size_t)(n0 + row) * ND + k0 + scol, &sB[chunk << 9]);
    }
    __syncthreads();
#pragma unroll
    for (int ks = 0; ks < 2; ++ks) {
      bf16x8 af[4], bfr[4];
#pragma unroll
      for (int mi = 0; mi < 4; ++mi)
        af[mi] = *(const bf16x8*)&sA[((wm << 6) + (mi << 4) + lr) * 64 + (ks << 5) + lk];
#pragma unroll
      for (int ni = 0; ni < 4; ++ni)
        bfr[ni] = *(const bf16x8*)&sB[((wn << 6) + (ni << 4) + lr) * 64 + (ks << 5) + lk];
#pragma unroll
      for (int mi = 0; mi < 4; ++mi)
#pragma unroll
        for (int ni = 0; ni < 4; ++ni)
          acc[mi][ni] = __builtin_amdgcn_mfma_f32_16x16x32_bf16(af[mi], bfr[ni], acc[mi][ni], 0, 0, 0);
    }
  }

  // ---- epilogue: two-pass f32 LDS stage + float4 stores ----
  const int rbase = (lane >> 4) << 2;
  float* stf = (float*)smem_raw;  // [64][132]
#pragma unroll
  for (int pass = 0; pass < 2; ++pass) {
    __syncthreads();
    if (wm == pass) {
#pragma unroll
      for (int mi = 0; mi < 4; ++mi) {
        const int rloc = (mi << 4) + rbase;  // 0..63 within half-tile
#pragma unroll
        for (int ni = 0; ni < 4; ++ni) {
          const int col = (wn << 6) + (ni << 4) + lr;
#pragma unroll
          for (int r = 0; r < 4; ++r) stf[(rloc + r) * 132 + col] = acc[mi][ni][r];
        }
      }
    }
    __syncthreads();
#pragma unroll
    for (int i = 0; i < 8; ++i) {
      const int g = (i << 8) + tid;           // 2048 granules: 64 rows x 32 segs
      const int row = g >> 5, seg = g & 31;
      const float4 v = *(const float4*)&stf[row * 132 + (seg << 2)];
      *(float4*)&out[(size_t)(m0 + (pass << 6) + row) * ND + n0 + (seg << 2)] = v;
    }
  }
}

// ---------------------------------------------------------------------------
extern "C" void kernel_launch(void* const* d_in, const int* in_sizes, int n_in,
                              void* d_out, int out_size, void* d_ws,
                              size_t ws_size, hipStream_t stream) {
  const float* x = (const float*)d_in[0];
  const float* Wq = (const float*)d_in[1];
  const float* Wk = (const float*)d_in[2];
  const float* Wv = (const float*)d_in[3];
  const float* Wo = (const float*)d_in[4];
  const int* pos = (const int*)d_in[5];
  float* out = (float*)d_out;

  // workspace layout (bf16 elements)
  bf16* xb = (bf16*)d_ws;                        // 8M  (B,S,D) converted x
  bf16* Wqb = xb + (size_t)NM * ND;              // 1M
  bf16* Wkb = Wqb + (size_t)ND * ND;             // 1M
  bf16* Wvb = Wkb + (size_t)ND * ND;             // 1M
  bf16* Wob = Wvb + (size_t)ND * ND;             // 1M
  bf16* Qw = Wob + (size_t)ND * ND;              // 8M (B,H,S,DK)
  bf16* Kw = Qw + (size_t)NM * NDK * NH;         // 8M (B,H,S,DK)
  bf16* Vw = Kw + (size_t)NM * NDK * NH;         // 8M (B,H,DK,S) transposed
  bf16* Aw = xb;                                 // overlay: x dead after qkv

  conv_kernel<<<6144, 256, 0, stream>>>(x, Wq, Wk, Wv, Wo, xb, Wqb, Wkb, Wvb, Wob);
  qkv_kernel<<<dim3(24, 64), 256, 0, stream>>>(xb, Wqb, Wkb, Wvb, pos, Qw, Kw, Vw);
  attn_kernel<<<dim3(8, 64), 256, 0, stream>>>(Qw, Kw, Vw, Aw);
  oproj_kernel<<<dim3(8, 64), 256, 0, stream>>>(Aw, Wob, out);
}